// Round 6
// baseline (377.169 us; speedup 1.0000x reference)
//
#include <hip/hip_runtime.h>

// WKV7 (RWKV-7) forward scan. T=2048, H=64, D=64.
// R6: R5's 8-slot global_load_lds ring kept. Changes:
//  - sched_barrier(0) per body REMOVED; the lgkmcnt wait is now tied to the
//    consumed Buf registers via "+v" asm operands (rule #18 satisfied by a
//    data dependency, not a full fence) -> y-tail of step t overlaps the
//    chain of step t+1.
//  - carried chain shortened: dec = s*e + vv*k precomputed during the sa
//    reduction; post-reduce update is ONE fma (was 3 serial).
//  - vmcnt bound corrected to 42 (stores count in vmcnt).

typedef float f32x4 __attribute__((ext_vector_type(4)));

constexpr int T_LEN = 2048;
constexpr int DD    = 64;
constexpr int HD    = 64 * 64;   // 4096

#define AS1 __attribute__((address_space(1)))
#define AS3 __attribute__((address_space(3)))

struct Buf { f32x4 r, e, k, a, b; float vv; };

__global__ __launch_bounds__(256)
void exp_kernel(const float4* __restrict__ w, float4* __restrict__ ew, int n4) {
  int i = blockIdx.x * blockDim.x + threadIdx.x;
  int stride = gridDim.x * blockDim.x;
  for (; i < n4; i += stride) {
    float4 x = w[i];
    float4 o;
    o.x = __expf(x.x); o.y = __expf(x.y); o.z = __expf(x.z); o.w = __expf(x.w);
    ew[i] = o;
  }
}

template<int CTRL>
__device__ __forceinline__ float dpp_add(float x) {
  int y = __builtin_amdgcn_update_dpp(0, __float_as_int(x), CTRL, 0xf, 0xf, true);
  return x + __int_as_float(y);
}

// Sum across the 16 lanes of a DPP row (all lanes end with the sum).
__device__ __forceinline__ float row16_reduce(float x) {
  x = dpp_add<0xB1>(x);    // quad_perm [1,0,3,2] : + lane^1
  x = dpp_add<0x4E>(x);    // quad_perm [2,3,0,1] : + lane^2
  x = dpp_add<0x141>(x);   // row_half_mirror    : + other quad
  x = dpp_add<0x140>(x);   // row_mirror         : + other half
  return x;
}

__device__ __forceinline__ void gload_lds(const float* g, const float* l) {
  __builtin_amdgcn_global_load_lds((const AS1 unsigned*)g, (AS3 unsigned*)l, 4, 0, 0);
}

__global__ __launch_bounds__(64, 1)
void wkv7_scan(const float* __restrict__ R, const float* __restrict__ EW,
               const float* __restrict__ K, const float* __restrict__ V,
               const float* __restrict__ A, const float* __restrict__ B,
               const float* __restrict__ S0, float* __restrict__ X,
               float* __restrict__ SOUT)
{
  // 8 slots x (5 vectors + v) x 64 floats = 3072 floats = 12 KB
  __shared__ float smem[3072];

  const int blk = blockIdx.x;          // 0..1023
  // XCD co-location: 8 whole heads (16 row-blocks each) per XCD for L2 reuse.
  const int xcd = blk & 7;
  const int m   = blk >> 3;            // 0..127
  const int h   = xcd * 8 + (m & 7);   // head 0..63
  const int br  = m >> 3;              // row block 0..15

  const int lane = threadIdx.x;        // 0..63
  const int cg   = lane & 15;          // cols [cg*4, cg*4+4)
  const int rl   = lane >> 4;          // local row 0..3
  const int row  = br * 4 + rl;        // 0..63
  const int c0   = cg * 4;

  const int laneoff = h * DD + lane;   // per-lane global offset, all 6 arrays

  const unsigned lb  = (unsigned)(uintptr_t)(AS3 float*)&smem[0];
  const unsigned vab = lb + (unsigned)(cg * 16);   // vector-read base
  const unsigned vvb = lb + (unsigned)(row * 4);   // v-read base (offset:1280)

  int yoff = (h * DD + row) * 4;       // byte offset into X, advances by HD*4

  f32x4 s;
  {
    const f32x4* sp = (const f32x4*)(S0 + (size_t)h * DD * DD + row * DD + c0);
    s = *sp;
  }

  auto stage = [&](int tt, int slot) {
    const size_t o = (size_t)tt * HD + laneoff;
    const float* l = &smem[slot * 384];
    gload_lds(R  + o, l);
    gload_lds(EW + o, l + 64);
    gload_lds(K  + o, l + 128);
    gload_lds(A  + o, l + 192);
    gload_lds(B  + o, l + 256);
    gload_lds(V  + o, l + 320);
  };

  auto lds_read = [&](Buf& d, int slot) {
    unsigned va = vab + (unsigned)(slot * 1536);
    unsigned vv = vvb + (unsigned)(slot * 1536);
    asm volatile(
      "ds_read_b128 %0, %6\n\t"
      "ds_read_b128 %1, %6 offset:256\n\t"
      "ds_read_b128 %2, %6 offset:512\n\t"
      "ds_read_b128 %3, %6 offset:768\n\t"
      "ds_read_b128 %4, %6 offset:1024\n\t"
      "ds_read_b32  %5, %7 offset:1280"
      : "=&v"(d.r), "=&v"(d.e), "=&v"(d.k), "=&v"(d.a), "=&v"(d.b), "=&v"(d.vv)
      : "v"(va), "v"(vv) : "memory");
  };

  // Wait for THIS buffer's ds_reads (issued one body earlier; the only DS ops
  // newer are the 6 just issued for nxt). Tied to the registers as a data
  // dependency so only true consumers are ordered after it — independent
  // VALU (prev step's y-tail) schedules freely around it.
  auto wait_buf = [&](Buf& d) {
    asm volatile("s_waitcnt lgkmcnt(6)"
                 : "+v"(d.r), "+v"(d.e), "+v"(d.k), "+v"(d.a), "+v"(d.b),
                   "+v"(d.vv));
  };

  auto body = [&](Buf& cur, Buf& nxt, int t) {
    // Stage t+1 landed iff outstanding vmem <= 42 (6 stores from bodies
    // t-6..t-1 + 36 loads of stages t+2..t+7 are newer than its last load).
    asm volatile("s_waitcnt vmcnt(42)" ::: "memory");
    lds_read(nxt, (t + 1) & 7);
    wait_buf(cur);

    const float vv = cur.vv;
    // decay part, independent of sa — overlaps the reduction:
    f32x4 dec;
    dec[0] = fmaf(s[0], cur.e[0], vv * cur.k[0]);
    dec[1] = fmaf(s[1], cur.e[1], vv * cur.k[1]);
    dec[2] = fmaf(s[2], cur.e[2], vv * cur.k[2]);
    dec[3] = fmaf(s[3], cur.e[3], vv * cur.k[3]);

    float p0 = fmaf(s[2], cur.a[2], s[0] * cur.a[0]);
    float p1 = fmaf(s[3], cur.a[3], s[1] * cur.a[1]);
    float sa = row16_reduce(p0 + p1);

    // ONE op after the reduction on the carried chain:
    s[0] = fmaf(sa, cur.b[0], dec[0]);
    s[1] = fmaf(sa, cur.b[1], dec[1]);
    s[2] = fmaf(sa, cur.b[2], dec[2]);
    s[3] = fmaf(sa, cur.b[3], dec[3]);

    float y0 = fmaf(s[2], cur.r[2], s[0] * cur.r[0]);
    float y1 = fmaf(s[3], cur.r[3], s[1] * cur.r[1]);
    float y  = row16_reduce(y0 + y1);
    // 16 lanes of a row group store the same value to the same address.
    asm volatile("global_store_dword %0, %1, %2"
                 :: "v"(yoff), "v"(y), "s"(X) : "memory");
    yoff += HD * 4;

    stage((t + 8) & (T_LEN - 1), t & 7);  // refill freed slot (dummy at tail)
  };

  // Prologue: fill the ring (stages 0..7, in order), then regs for step 0.
  for (int i = 0; i < 8; ++i) {
    stage(i, i);
    __builtin_amdgcn_sched_barrier(0);   // keep stage issue order = count order
  }
  asm volatile("s_waitcnt vmcnt(42)" ::: "memory");  // stage 0 done (42 newer)

  Buf RA, RB;
  lds_read(RA, 0);

  for (int t = 0; t < T_LEN; t += 2) {
    body(RA, RB, t);
    body(RB, RA, t + 1);
  }

  *(f32x4*)(SOUT + (size_t)h * DD * DD + row * DD + c0) = s;
}

extern "C" void kernel_launch(void* const* d_in, const int* in_sizes, int n_in,
                              void* d_out, int out_size, void* d_ws, size_t ws_size,
                              hipStream_t stream) {
  // setup_inputs order: seq_length, r, w, k, v, a, b, state2
  const float* r  = (const float*)d_in[1];
  const float* w  = (const float*)d_in[2];
  const float* k  = (const float*)d_in[3];
  const float* v  = (const float*)d_in[4];
  const float* a  = (const float*)d_in[5];
  const float* b  = (const float*)d_in[6];
  const float* s0 = (const float*)d_in[7];

  float* x    = (float*)d_out;                     // (T, H, 1, D)
  float* sout = x + (size_t)T_LEN * HD;            // (H, D, D)

  float* ew = (float*)d_ws;
  (void)ws_size; (void)in_sizes; (void)n_in;

  int n4 = T_LEN * HD / 4;
  hipLaunchKernelGGL(exp_kernel, dim3(1024), dim3(256), 0, stream,
                     (const float4*)w, (float4*)ew, n4);
  hipLaunchKernelGGL(wkv7_scan, dim3(1024), dim3(64), 0, stream,
                     r, ew, k, v, a, b, s0, x, sout);
}